// Round 2
// baseline (3641.835 us; speedup 1.0000x reference)
//
#include <hip/hip_runtime.h>
#include <hip/hip_bf16.h>
#include <math.h>

#define E_DIM 512
#define H_DIM 1024
#define V_DIM 50257
#define NSTEPS 19
#define NB_LOG 1024      // logits blocks (4 waves each -> 4096 waves)
#define NB_GATES 256     // gates blocks
#define CAND_CAP 1024
#define EPS_SCALE 0.00390625f   // 2^-8: 2x margin over bf16 rel err 2^-9

// ---- workspace layout (bytes) ----
#define OFF_X     0          // 512 f
#define OFF_H     2048       // 1024 f
#define OFF_C     6144       // 1024 f
#define OFF_GATES 10240      // 4096 f
#define OFF_CNT1  26624      // u32
#define OFF_CNT2  26688      // u32
#define OFF_PM    26752      // 1024 f   per-block max-lower-bound
#define OFF_PART  30848      // 1024 u64 per-block packed argmax (f32 path)
#define OFF_U     39040      // 50257 f upper bounds (+pad)
#define OFF_L     240128     // 50257 f lower bounds (+pad)
#define OFF_WB    441216     // bf16 W_lin, 50257*1024*2 bytes
#define WS_NEEDED (441216ull + (unsigned long long)V_DIM * 1024ull * 2ull)

__device__ inline unsigned fmap(float f) {
    unsigned u = __float_as_uint(f);
    return (u & 0x80000000u) ? ~u : (u | 0x80000000u);
}
__device__ inline float bf_lo(unsigned u) { return __uint_as_float(u << 16); }
__device__ inline float bf_hi(unsigned u) { return __uint_as_float(u & 0xFFFF0000u); }
__device__ inline unsigned f2bf(float f) {  // round-to-nearest-even, finite inputs
    unsigned u = __float_as_uint(f);
    return (u + 0x7FFFu + ((u >> 16) & 1u)) >> 16;
}

// ---------------- init: x = inp, h = c = 0, counters = 0 ----------------
__global__ void init_kernel(const float* __restrict__ inp,
                            float* __restrict__ x, float* __restrict__ h,
                            float* __restrict__ c,
                            unsigned* cnt1, unsigned* cnt2) {
    int i = threadIdx.x;                 // 1024 threads, 1 block
    if (i < E_DIM) x[i] = inp[i];
    h[i] = 0.f; c[i] = 0.f;
    if (i == 0) { *cnt1 = 0u; *cnt2 = 0u; }
}

// ---------------- gates matvec + fused LSTM cell (last block) ----------------
__global__ void gates_cell_kernel(const float* __restrict__ Wih,
                                  const float* __restrict__ Whh,
                                  const float* __restrict__ bih,
                                  const float* __restrict__ bhh,
                                  const float* __restrict__ x,
                                  float* __restrict__ h,
                                  float* __restrict__ c,
                                  float* __restrict__ gates,
                                  unsigned* cnt) {
    const int tid = threadIdx.x, lane = tid & 63, wave = tid >> 6;
    const int gw = blockIdx.x * 4 + wave;
    const int NW = NB_GATES * 4;

    const float4* x4 = (const float4*)x;
    const float4* h4 = (const float4*)h;
    float4 xr[2], hr[4];
#pragma unroll
    for (int j = 0; j < 2; ++j) xr[j] = x4[lane + j * 64];
#pragma unroll
    for (int j = 0; j < 4; ++j) hr[j] = h4[lane + j * 64];

    for (int row = gw; row < 4 * H_DIM; row += NW) {
        const float4* wi = (const float4*)(Wih + (size_t)row * E_DIM);
        const float4* wh = (const float4*)(Whh + (size_t)row * H_DIM);
        float s = 0.f;
#pragma unroll
        for (int j = 0; j < 2; ++j) {
            float4 w = wi[lane + j * 64];
            s += w.x * xr[j].x + w.y * xr[j].y + w.z * xr[j].z + w.w * xr[j].w;
        }
#pragma unroll
        for (int j = 0; j < 4; ++j) {
            float4 w = wh[lane + j * 64];
            s += w.x * hr[j].x + w.y * hr[j].y + w.z * hr[j].z + w.w * hr[j].w;
        }
#pragma unroll
        for (int off = 32; off; off >>= 1) s += __shfl_xor(s, off, 64);
        if (lane == 0) gates[row] = s + bih[row] + bhh[row];
    }

    __shared__ int isLast;
    __threadfence();
    __syncthreads();
    if (tid == 0) {
        unsigned o = atomicAdd(cnt, 1u);
        isLast = (o == (unsigned)(gridDim.x - 1));
    }
    __syncthreads();
    if (!isLast) return;
    __threadfence();
    for (int j = tid; j < H_DIM; j += 256) {
        float iv = gates[j];
        float fv = gates[j + H_DIM];
        float gv = gates[j + 2 * H_DIM];
        float ov = gates[j + 3 * H_DIM];
        iv = 1.0f / (1.0f + expf(-iv));
        fv = 1.0f / (1.0f + expf(-fv));
        gv = tanhf(gv);
        ov = 1.0f / (1.0f + expf(-ov));
        float cv = fv * c[j] + iv * gv;
        c[j] = cv;
        h[j] = ov * tanhf(cv);
    }
    if (tid == 0) *cnt = 0u;
}

// ---------------- fp32 logits (+optional bf16 convert) + fused finalize ----------------
__global__ void logits_f32_kernel(const float* __restrict__ Wlin,
                                  const float* __restrict__ blin,
                                  const float* __restrict__ h,
                                  const float* __restrict__ emb,
                                  unsigned* __restrict__ Wb, int doConv,
                                  unsigned long long* __restrict__ partials,
                                  float* __restrict__ x, int* __restrict__ tok_out,
                                  unsigned* cnt) {
    const int tid = threadIdx.x, lane = tid & 63, wave = tid >> 6;
    const int gw = blockIdx.x * 4 + wave;

    const float4* h4 = (const float4*)h;
    float4 hr[2][2];
#pragma unroll
    for (int j = 0; j < 2; ++j) {
        int q = lane + 64 * j;
        hr[j][0] = h4[2 * q];
        hr[j][1] = h4[2 * q + 1];
    }

    float best = -INFINITY;
    int bidx = 0x7fffffff;
    for (int row = gw; row < V_DIM; row += NB_LOG * 4) {
        const float4* w4 = (const float4*)(Wlin + (size_t)row * H_DIM);
        float s = 0.f;
#pragma unroll
        for (int j = 0; j < 2; ++j) {
            int q = lane + 64 * j;
            float4 A = w4[2 * q];
            float4 B = w4[2 * q + 1];
            s = fmaf(A.x, hr[j][0].x, s); s = fmaf(A.y, hr[j][0].y, s);
            s = fmaf(A.z, hr[j][0].z, s); s = fmaf(A.w, hr[j][0].w, s);
            s = fmaf(B.x, hr[j][1].x, s); s = fmaf(B.y, hr[j][1].y, s);
            s = fmaf(B.z, hr[j][1].z, s); s = fmaf(B.w, hr[j][1].w, s);
            if (doConv) {
                uint4 p;
                p.x = f2bf(A.x) | (f2bf(A.y) << 16);
                p.y = f2bf(A.z) | (f2bf(A.w) << 16);
                p.z = f2bf(B.x) | (f2bf(B.y) << 16);
                p.w = f2bf(B.z) | (f2bf(B.w) << 16);
                ((uint4*)(Wb + (size_t)row * 512))[q] = p;
            }
        }
#pragma unroll
        for (int off = 32; off; off >>= 1) s += __shfl_xor(s, off, 64);
        s += blin[row];
        if (s > best) { best = s; bidx = row; }
    }

    __shared__ float bv[4];
    __shared__ int bi[4];
    __shared__ int isLast;
    if (lane == 0) { bv[wave] = best; bi[wave] = bidx; }
    __syncthreads();
    if (tid == 0) {
        float B = bv[0]; int I = bi[0];
        for (int w = 1; w < 4; ++w)
            if (bv[w] > B || (bv[w] == B && bi[w] < I)) { B = bv[w]; I = bi[w]; }
        partials[blockIdx.x] =
            ((unsigned long long)fmap(B) << 32) | (unsigned)(0xFFFFFFFFu - (unsigned)I);
        __threadfence();
        unsigned o = atomicAdd(cnt, 1u);
        isLast = (o == (unsigned)(gridDim.x - 1));
    }
    __syncthreads();
    if (!isLast) return;
    __threadfence();

    unsigned long long bp = 0ull;
    for (int i = tid; i < NB_LOG; i += 256) {
        unsigned long long p = partials[i];
        if (p > bp) bp = p;
    }
#pragma unroll
    for (int off = 32; off; off >>= 1) {
        unsigned long long o = __shfl_xor(bp, off, 64);
        if (o > bp) bp = o;
    }
    __shared__ unsigned long long sb[4];
    __shared__ int stok;
    if (lane == 0) sb[wave] = bp;
    __syncthreads();
    if (tid == 0) {
        unsigned long long B = sb[0];
        for (int w = 1; w < 4; ++w) if (sb[w] > B) B = sb[w];
        int tok = (int)(0xFFFFFFFFu - (unsigned)(B & 0xFFFFFFFFu));
        stok = tok;
        *tok_out = tok;
    }
    __syncthreads();
    int tok = stok;
    const float4* e4 = (const float4*)(emb + (size_t)tok * E_DIM);
    float4* xo = (float4*)x;
    if (tid < E_DIM / 4) xo[tid] = e4[tid];
    if (tid == 0) *cnt = 0u;
}

// ------- bf16 logits with exact-rescue argmax + fused finalize -------
__global__ void logits_bf16_kernel(const unsigned* __restrict__ Wb,
                                   const float* __restrict__ Wlin,
                                   const float* __restrict__ blin,
                                   const float* __restrict__ h,
                                   const float* __restrict__ emb,
                                   float* __restrict__ u_arr, float* __restrict__ l_arr,
                                   float* __restrict__ partialM,
                                   float* __restrict__ x, int* __restrict__ tok_out,
                                   unsigned* cnt) {
    const int tid = threadIdx.x, lane = tid & 63, wave = tid >> 6;
    const int gw = blockIdx.x * 4 + wave;

    const float4* h4 = (const float4*)h;
    float4 hr[2][2], ha[2][2];
#pragma unroll
    for (int j = 0; j < 2; ++j) {
        int q = lane + 64 * j;
        hr[j][0] = h4[2 * q];
        hr[j][1] = h4[2 * q + 1];
        ha[j][0] = make_float4(fabsf(hr[j][0].x), fabsf(hr[j][0].y), fabsf(hr[j][0].z), fabsf(hr[j][0].w));
        ha[j][1] = make_float4(fabsf(hr[j][1].x), fabsf(hr[j][1].y), fabsf(hr[j][1].z), fabsf(hr[j][1].w));
    }

    float maxl = -INFINITY;
    for (int row = gw; row < V_DIM; row += NB_LOG * 4) {
        const uint4* wb4 = (const uint4*)(Wb + (size_t)row * 512);
        float s = 0.f, a = 0.f;
#pragma unroll
        for (int j = 0; j < 2; ++j) {
            uint4 p = wb4[lane + 64 * j];
            float w0 = bf_lo(p.x), w1 = bf_hi(p.x), w2 = bf_lo(p.y), w3 = bf_hi(p.y);
            float w4_ = bf_lo(p.z), w5 = bf_hi(p.z), w6 = bf_lo(p.w), w7 = bf_hi(p.w);
            float4 h0 = hr[j][0], h1 = hr[j][1], a0 = ha[j][0], a1 = ha[j][1];
            s = fmaf(w0, h0.x, s); a = fmaf(fabsf(w0), a0.x, a);
            s = fmaf(w1, h0.y, s); a = fmaf(fabsf(w1), a0.y, a);
            s = fmaf(w2, h0.z, s); a = fmaf(fabsf(w2), a0.z, a);
            s = fmaf(w3, h0.w, s); a = fmaf(fabsf(w3), a0.w, a);
            s = fmaf(w4_, h1.x, s); a = fmaf(fabsf(w4_), a1.x, a);
            s = fmaf(w5, h1.y, s); a = fmaf(fabsf(w5), a1.y, a);
            s = fmaf(w6, h1.z, s); a = fmaf(fabsf(w6), a1.z, a);
            s = fmaf(w7, h1.w, s); a = fmaf(fabsf(w7), a1.w, a);
        }
#pragma unroll
        for (int off = 32; off; off >>= 1) {
            s += __shfl_xor(s, off, 64);
            a += __shfl_xor(a, off, 64);
        }
        float L = s + blin[row];
        float e = a * EPS_SCALE;
        if (lane == 0) { u_arr[row] = L + e; l_arr[row] = L - e; }
        maxl = fmaxf(maxl, L - e);
    }

    __shared__ float wmax[4];
    __shared__ int isLast;
    __threadfence();            // flush u/l before the release atomic
    if (lane == 0) wmax[wave] = maxl;
    __syncthreads();
    if (tid == 0) {
        float bm = fmaxf(fmaxf(wmax[0], wmax[1]), fmaxf(wmax[2], wmax[3]));
        partialM[blockIdx.x] = bm;
        __threadfence();
        unsigned o = atomicAdd(cnt, 1u);
        isLast = (o == (unsigned)(gridDim.x - 1));
    }
    __syncthreads();
    if (!isLast) return;
    __threadfence();            // acquire side

    // 1) global threshold M = max over blocks of (max lower bound)
    float m = -INFINITY;
    for (int i = tid; i < NB_LOG; i += 256) m = fmaxf(m, partialM[i]);
#pragma unroll
    for (int off = 32; off; off >>= 1) m = fmaxf(m, __shfl_xor(m, off, 64));
    __shared__ float wm2[4];
    __shared__ float sM;
    __shared__ int scnt;
    __shared__ int clist[CAND_CAP];
    if (lane == 0) wm2[wave] = m;
    __syncthreads();
    if (tid == 0) {
        sM = fmaxf(fmaxf(wm2[0], wm2[1]), fmaxf(wm2[2], wm2[3]));
        scnt = 0;
    }
    __syncthreads();
    float M = sM;

    // 2) collect candidate rows: upper bound >= M
    for (int r = tid; r < V_DIM; r += 256) {
        if (u_arr[r] >= M) {
            int p = atomicAdd(&scnt, 1);
            if (p < CAND_CAP) clist[p] = r;
        }
    }
    __syncthreads();
    int n = min(scnt, CAND_CAP);

    // 3) exact fp32 recompute of candidates, packed argmax (lowest idx on tie)
    unsigned long long bestp = 0ull;
    for (int ci = wave; ci < n; ci += 4) {
        int row = clist[ci];
        const float4* w4 = (const float4*)(Wlin + (size_t)row * H_DIM);
        float s = 0.f;
#pragma unroll
        for (int j = 0; j < 2; ++j) {
            int q = lane + 64 * j;
            float4 A = w4[2 * q];
            float4 B = w4[2 * q + 1];
            s = fmaf(A.x, hr[j][0].x, s); s = fmaf(A.y, hr[j][0].y, s);
            s = fmaf(A.z, hr[j][0].z, s); s = fmaf(A.w, hr[j][0].w, s);
            s = fmaf(B.x, hr[j][1].x, s); s = fmaf(B.y, hr[j][1].y, s);
            s = fmaf(B.z, hr[j][1].z, s); s = fmaf(B.w, hr[j][1].w, s);
        }
#pragma unroll
        for (int off = 32; off; off >>= 1) s += __shfl_xor(s, off, 64);
        s += blin[row];
        unsigned long long p =
            ((unsigned long long)fmap(s) << 32) | (unsigned)(0xFFFFFFFFu - (unsigned)row);
        if (p > bestp) bestp = p;
    }
    __shared__ unsigned long long sbp[4];
    __shared__ int stok;
    if (lane == 0) sbp[wave] = bestp;
    __syncthreads();
    if (tid == 0) {
        unsigned long long B = sbp[0];
        for (int w = 1; w < 4; ++w) if (sbp[w] > B) B = sbp[w];
        int tok = (int)(0xFFFFFFFFu - (unsigned)(B & 0xFFFFFFFFu));
        stok = tok;
        *tok_out = tok;
    }
    __syncthreads();
    int tok = stok;
    const float4* e4 = (const float4*)(emb + (size_t)tok * E_DIM);
    float4* xo = (float4*)x;
    if (tid < E_DIM / 4) xo[tid] = e4[tid];
    if (tid == 0) *cnt = 0u;
}

extern "C" void kernel_launch(void* const* d_in, const int* in_sizes, int n_in,
                              void* d_out, int out_size, void* d_ws, size_t ws_size,
                              hipStream_t stream) {
    const float* inp  = (const float*)d_in[0];
    const float* Wih  = (const float*)d_in[1];
    const float* Whh  = (const float*)d_in[2];
    const float* bih  = (const float*)d_in[3];
    const float* bhh  = (const float*)d_in[4];
    const float* emb  = (const float*)d_in[5];
    const float* Wlin = (const float*)d_in[6];
    const float* blin = (const float*)d_in[7];
    int* toks = (int*)d_out;

    char* ws = (char*)d_ws;
    float* x     = (float*)(ws + OFF_X);
    float* h     = (float*)(ws + OFF_H);
    float* c     = (float*)(ws + OFF_C);
    float* gates = (float*)(ws + OFF_GATES);
    unsigned* cnt1 = (unsigned*)(ws + OFF_CNT1);
    unsigned* cnt2 = (unsigned*)(ws + OFF_CNT2);
    float* pM    = (float*)(ws + OFF_PM);
    unsigned long long* partials = (unsigned long long*)(ws + OFF_PART);
    float* u_arr = (float*)(ws + OFF_U);
    float* l_arr = (float*)(ws + OFF_L);
    unsigned* Wb = (unsigned*)(ws + OFF_WB);

    const int useBf = (ws_size >= WS_NEEDED) ? 1 : 0;

    init_kernel<<<1, 1024, 0, stream>>>(inp, x, h, c, cnt1, cnt2);

    for (int step = 0; step < NSTEPS; ++step) {
        gates_cell_kernel<<<NB_GATES, 256, 0, stream>>>(Wih, Whh, bih, bhh, x, h, c, gates, cnt1);
        if (step == 0 || !useBf) {
            logits_f32_kernel<<<NB_LOG, 256, 0, stream>>>(
                Wlin, blin, h, emb, Wb, (step == 0 && useBf) ? 1 : 0,
                partials, x, toks + step, cnt2);
        } else {
            logits_bf16_kernel<<<NB_LOG, 256, 0, stream>>>(
                Wb, Wlin, blin, h, emb, u_arr, l_arr, pM, x, toks + step, cnt2);
        }
    }
}

// Round 3
// 861.212 us; speedup vs baseline: 4.2287x; 4.2287x over previous
//
#include <hip/hip_runtime.h>
#include <hip/hip_bf16.h>
#include <math.h>

#define E_DIM 512
#define H_DIM 1024
#define V_DIM 50257
#define NSTEPS 19
#define NB_LOG 1024      // logits blocks (4 waves each)
#define NB_GATES 256
#define RPW 13           // rows per wave, bf16 kernel: 4096 waves * 13 = 53248 >= V
#define CAND_CAP 512
#define EPS_SCALE 0.00390625f   // 2^-8; true bf16 bound is ~2^-9 -> 2x margin

// ---- workspace layout (bytes) ----
#define OFF_X      0          // 512 f
#define OFF_H      4096       // 1024 f
#define OFF_C      8192       // 1024 f
#define OFF_GATES  16384      // 4096 f
#define OFF_HN     32768      // 1 f  (||h||_2)
#define OFF_PART   33024      // 1024 u64 (step-0 packed argmax partials)
#define OFF_PBLOCK 41216      // 1024 f   (bf16 per-block max lower bound)
#define OFF_NRM    49152      // 50257 f  ||w~_r||_2  (pad to 204800)
#define OFF_LE     253952     // 50257 float2 {L_r, e_r} (pad to 409600)
#define OFF_WB     663552     // bf16 W_lin, 50257*1024*2 B
#define WS_NEEDED  (663552ull + (unsigned long long)V_DIM * H_DIM * 2ull)

__device__ inline unsigned fmap(float f) {
    unsigned u = __float_as_uint(f);
    return (u & 0x80000000u) ? ~u : (u | 0x80000000u);
}
__device__ inline float bf_lo(unsigned u) { return __uint_as_float(u << 16); }
__device__ inline float bf_hi(unsigned u) { return __uint_as_float(u & 0xFFFF0000u); }
__device__ inline unsigned f2bf(float f) {  // RNE, finite
    unsigned u = __float_as_uint(f);
    return (u + 0x7FFFu + ((u >> 16) & 1u)) >> 16;
}

// exact fp32 row dot (wave-collective, result broadcast to all lanes)
__device__ inline float row_dot_f32(const float* __restrict__ Wrow,
                                    const float4 hr[2][2], int lane) {
    const float4* w4 = (const float4*)Wrow;
    float s = 0.f;
#pragma unroll
    for (int j = 0; j < 2; ++j) {
        int q = lane + 64 * j;
        float4 A = w4[2 * q];
        float4 B = w4[2 * q + 1];
        s = fmaf(A.x, hr[j][0].x, s); s = fmaf(A.y, hr[j][0].y, s);
        s = fmaf(A.z, hr[j][0].z, s); s = fmaf(A.w, hr[j][0].w, s);
        s = fmaf(B.x, hr[j][1].x, s); s = fmaf(B.y, hr[j][1].y, s);
        s = fmaf(B.z, hr[j][1].z, s); s = fmaf(B.w, hr[j][1].w, s);
    }
#pragma unroll
    for (int off = 32; off; off >>= 1) s += __shfl_xor(s, off, 64);
    return s;
}

__device__ inline void load_h_frag(const float* __restrict__ h, float4 hr[2][2], int lane) {
    const float4* h4 = (const float4*)h;
#pragma unroll
    for (int j = 0; j < 2; ++j) {
        int q = lane + 64 * j;
        hr[j][0] = h4[2 * q];
        hr[j][1] = h4[2 * q + 1];
    }
}

// ---------------- init ----------------
__global__ void init_kernel(const float* __restrict__ inp,
                            float* __restrict__ x, float* __restrict__ h,
                            float* __restrict__ c) {
    int i = threadIdx.x;  // 1024
    if (i < E_DIM) x[i] = inp[i];
    h[i] = 0.f; c[i] = 0.f;
}

// ---------------- gates matvec ----------------
__global__ void gates_kernel(const float* __restrict__ Wih,
                             const float* __restrict__ Whh,
                             const float* __restrict__ bih,
                             const float* __restrict__ bhh,
                             const float* __restrict__ x,
                             const float* __restrict__ h,
                             float* __restrict__ gates) {
    const int lane = threadIdx.x & 63, wave = threadIdx.x >> 6;
    const int gw = blockIdx.x * 4 + wave;
    const int NW = NB_GATES * 4;

    const float4* x4 = (const float4*)x;
    const float4* h4 = (const float4*)h;
    float4 xr[2], hr[4];
#pragma unroll
    for (int j = 0; j < 2; ++j) xr[j] = x4[lane + j * 64];
#pragma unroll
    for (int j = 0; j < 4; ++j) hr[j] = h4[lane + j * 64];

    for (int row = gw; row < 4 * H_DIM; row += NW) {
        const float4* wi = (const float4*)(Wih + (size_t)row * E_DIM);
        const float4* wh = (const float4*)(Whh + (size_t)row * H_DIM);
        float s = 0.f;
#pragma unroll
        for (int j = 0; j < 2; ++j) {
            float4 w = wi[lane + j * 64];
            s = fmaf(w.x, xr[j].x, s); s = fmaf(w.y, xr[j].y, s);
            s = fmaf(w.z, xr[j].z, s); s = fmaf(w.w, xr[j].w, s);
        }
#pragma unroll
        for (int j = 0; j < 4; ++j) {
            float4 w = wh[lane + j * 64];
            s = fmaf(w.x, hr[j].x, s); s = fmaf(w.y, hr[j].y, s);
            s = fmaf(w.z, hr[j].z, s); s = fmaf(w.w, hr[j].w, s);
        }
#pragma unroll
        for (int off = 32; off; off >>= 1) s += __shfl_xor(s, off, 64);
        if (lane == 0) gates[row] = s + bih[row] + bhh[row];
    }
}

// ---------------- LSTM cell + ||h||_2 ----------------
__global__ void cell_kernel(const float* __restrict__ gates,
                            float* __restrict__ c, float* __restrict__ h,
                            float* __restrict__ hn) {
    int j = threadIdx.x;  // 1024 threads, 1 block
    float iv = gates[j];
    float fv = gates[j + H_DIM];
    float gv = gates[j + 2 * H_DIM];
    float ov = gates[j + 3 * H_DIM];
    iv = 1.0f / (1.0f + expf(-iv));
    fv = 1.0f / (1.0f + expf(-fv));
    gv = tanhf(gv);
    ov = 1.0f / (1.0f + expf(-ov));
    float cv = fv * c[j] + iv * gv;
    c[j] = cv;
    float hv = ov * tanhf(cv);
    h[j] = hv;

    float sq = hv * hv;
#pragma unroll
    for (int off = 32; off; off >>= 1) sq += __shfl_xor(sq, off, 64);
    __shared__ float ws[16];
    int lane = j & 63, wv = j >> 6;
    if (lane == 0) ws[wv] = sq;
    __syncthreads();
    if (j == 0) {
        float t = 0.f;
        for (int w = 0; w < 16; ++w) t += ws[w];
        *hn = sqrtf(t);
    }
}

// ---------------- step-0: fp32 logits + bf16 convert + ||w~||_2 + block argmax ----------------
__global__ void logits_f32_kernel(const float* __restrict__ Wlin,
                                  const float* __restrict__ blin,
                                  const float* __restrict__ h,
                                  unsigned* __restrict__ Wb,
                                  float* __restrict__ nrm, int doConv,
                                  unsigned long long* __restrict__ partials) {
    const int tid = threadIdx.x, lane = tid & 63, wave = tid >> 6;
    const int gw = blockIdx.x * 4 + wave;

    float4 hr[2][2];
    load_h_frag(h, hr, lane);

    float best = -INFINITY;
    int bidx = 0x7fffffff;
    for (int row = gw; row < V_DIM; row += NB_LOG * 4) {
        const float4* w4 = (const float4*)(Wlin + (size_t)row * H_DIM);
        float s = 0.f, s2 = 0.f;
#pragma unroll
        for (int j = 0; j < 2; ++j) {
            int q = lane + 64 * j;
            float4 A = w4[2 * q];
            float4 B = w4[2 * q + 1];
            s = fmaf(A.x, hr[j][0].x, s); s = fmaf(A.y, hr[j][0].y, s);
            s = fmaf(A.z, hr[j][0].z, s); s = fmaf(A.w, hr[j][0].w, s);
            s = fmaf(B.x, hr[j][1].x, s); s = fmaf(B.y, hr[j][1].y, s);
            s = fmaf(B.z, hr[j][1].z, s); s = fmaf(B.w, hr[j][1].w, s);
            if (doConv) {
                unsigned b0 = f2bf(A.x), b1 = f2bf(A.y), b2 = f2bf(A.z), b3 = f2bf(A.w);
                unsigned b4 = f2bf(B.x), b5 = f2bf(B.y), b6 = f2bf(B.z), b7 = f2bf(B.w);
                uint4 p;
                p.x = b0 | (b1 << 16); p.y = b2 | (b3 << 16);
                p.z = b4 | (b5 << 16); p.w = b6 | (b7 << 16);
                ((uint4*)(Wb + (size_t)row * 512))[q] = p;
                float w0 = bf_lo(p.x), w1 = bf_hi(p.x), w2 = bf_lo(p.y), w3 = bf_hi(p.y);
                float w4_ = bf_lo(p.z), w5 = bf_hi(p.z), w6 = bf_lo(p.w), w7 = bf_hi(p.w);
                s2 = fmaf(w0, w0, s2); s2 = fmaf(w1, w1, s2);
                s2 = fmaf(w2, w2, s2); s2 = fmaf(w3, w3, s2);
                s2 = fmaf(w4_, w4_, s2); s2 = fmaf(w5, w5, s2);
                s2 = fmaf(w6, w6, s2); s2 = fmaf(w7, w7, s2);
            }
        }
#pragma unroll
        for (int off = 32; off; off >>= 1) {
            s += __shfl_xor(s, off, 64);
            if (doConv) s2 += __shfl_xor(s2, off, 64);
        }
        if (doConv && lane == 0) nrm[row] = sqrtf(s2);
        s += blin[row];
        if (s > best) { best = s; bidx = row; }
    }

    __shared__ float bv[4];
    __shared__ int bi[4];
    if (lane == 0) { bv[wave] = best; bi[wave] = bidx; }
    __syncthreads();
    if (tid == 0) {
        float B = bv[0]; int I = bi[0];
        for (int w = 1; w < 4; ++w)
            if (bv[w] > B || (bv[w] == B && bi[w] < I)) { B = bv[w]; I = bi[w]; }
        partials[blockIdx.x] =
            ((unsigned long long)fmap(B) << 32) | (unsigned)(0xFFFFFFFFu - (unsigned)I);
    }
}

// ---------------- step-0 finalize: reduce partials, token, emb gather ----------------
__global__ void finalize_f32_kernel(const unsigned long long* __restrict__ partials,
                                    const float* __restrict__ emb,
                                    float* __restrict__ x, int* __restrict__ tok_out) {
    const int lane = threadIdx.x & 63, wave = threadIdx.x >> 6;
    unsigned long long best = 0ull;
    for (int i = threadIdx.x; i < NB_LOG; i += 256) {
        unsigned long long p = partials[i];
        if (p > best) best = p;
    }
#pragma unroll
    for (int off = 32; off; off >>= 1) {
        unsigned long long o = __shfl_xor(best, off, 64);
        if (o > best) best = o;
    }
    __shared__ unsigned long long sb[4];
    __shared__ int stok;
    if (lane == 0) sb[wave] = best;
    __syncthreads();
    if (threadIdx.x == 0) {
        unsigned long long B = sb[0];
        for (int w = 1; w < 4; ++w) if (sb[w] > B) B = sb[w];
        int tok = (int)(0xFFFFFFFFu - (unsigned)(B & 0xFFFFFFFFu));
        *tok_out = tok;
        stok = tok;
    }
    __syncthreads();
    int tok = stok;
    const float4* e4 = (const float4*)(emb + (size_t)tok * E_DIM);
    float4* x4 = (float4*)x;
    if (threadIdx.x < E_DIM / 4) x4[threadIdx.x] = e4[threadIdx.x];
}

// ---------------- bf16 logits: L_r, e_r, per-block max lower bound ----------------
__global__ void logits_bf16_kernel(const unsigned* __restrict__ Wb,
                                   const float* __restrict__ blin,
                                   const float* __restrict__ h,
                                   const float* __restrict__ nrm,
                                   const float* __restrict__ hn,
                                   float2* __restrict__ LE,
                                   float* __restrict__ pblock) {
    const int tid = threadIdx.x, lane = tid & 63, wave = tid >> 6;
    const int wid = blockIdx.x * 4 + wave;
    const int r0 = wid * RPW;
    int nrows = V_DIM - r0;
    nrows = nrows < 0 ? 0 : (nrows > RPW ? RPW : nrows);

    float4 hr[2][2];
    load_h_frag(h, hr, lane);
    const float K = EPS_SCALE * (*hn);

    const uint4* base = (const uint4*)(Wb + (size_t)r0 * 512);  // 128 uint4/row
    uint4 p0, p1;
    if (nrows > 0) { p0 = base[lane]; p1 = base[lane + 64]; }

    float maxl = -INFINITY;
    for (int k = 0; k < nrows; ++k) {
        uint4 c0 = p0, c1 = p1;
        if (k + 1 < nrows) {
            const uint4* nb = base + (size_t)(k + 1) * 128;
            p0 = nb[lane]; p1 = nb[lane + 64];
        }
        float s = 0.f;
        {
            float w0 = bf_lo(c0.x), w1 = bf_hi(c0.x), w2 = bf_lo(c0.y), w3 = bf_hi(c0.y);
            float w4_ = bf_lo(c0.z), w5 = bf_hi(c0.z), w6 = bf_lo(c0.w), w7 = bf_hi(c0.w);
            s = fmaf(w0, hr[0][0].x, s); s = fmaf(w1, hr[0][0].y, s);
            s = fmaf(w2, hr[0][0].z, s); s = fmaf(w3, hr[0][0].w, s);
            s = fmaf(w4_, hr[0][1].x, s); s = fmaf(w5, hr[0][1].y, s);
            s = fmaf(w6, hr[0][1].z, s); s = fmaf(w7, hr[0][1].w, s);
        }
        {
            float w0 = bf_lo(c1.x), w1 = bf_hi(c1.x), w2 = bf_lo(c1.y), w3 = bf_hi(c1.y);
            float w4_ = bf_lo(c1.z), w5 = bf_hi(c1.z), w6 = bf_lo(c1.w), w7 = bf_hi(c1.w);
            s = fmaf(w0, hr[1][0].x, s); s = fmaf(w1, hr[1][0].y, s);
            s = fmaf(w2, hr[1][0].z, s); s = fmaf(w3, hr[1][0].w, s);
            s = fmaf(w4_, hr[1][1].x, s); s = fmaf(w5, hr[1][1].y, s);
            s = fmaf(w6, hr[1][1].z, s); s = fmaf(w7, hr[1][1].w, s);
        }
#pragma unroll
        for (int off = 32; off; off >>= 1) s += __shfl_xor(s, off, 64);
        int r = r0 + k;
        float L = s + blin[r];
        float e = K * nrm[r];
        if (lane == 0) LE[r] = make_float2(L, e);
        maxl = fmaxf(maxl, L - e);
    }

    __shared__ float wm[4];
    if (lane == 0) wm[wave] = maxl;
    __syncthreads();
    if (tid == 0)
        pblock[blockIdx.x] = fmaxf(fmaxf(wm[0], wm[1]), fmaxf(wm[2], wm[3]));
}

// ---------------- bf16 finalize: M, candidates, exact rescue, token, emb ----------------
__global__ void finalize_bf16_kernel(const float2* __restrict__ LE,
                                     const float* __restrict__ pblock,
                                     const float* __restrict__ Wlin,
                                     const float* __restrict__ blin,
                                     const float* __restrict__ h,
                                     const float* __restrict__ emb,
                                     float* __restrict__ x, int* __restrict__ tok_out) {
    const int tid = threadIdx.x;          // 1024 threads
    const int lane = tid & 63, wv = tid >> 6;  // 16 waves

    // 1) M = max over blocks of (block max lower bound)
    float m = (tid < NB_LOG) ? pblock[tid] : -INFINITY;
#pragma unroll
    for (int off = 32; off; off >>= 1) m = fmaxf(m, __shfl_xor(m, off, 64));
    __shared__ float wmx[16];
    __shared__ float sM;
    __shared__ int scnt, sovf;
    __shared__ int clist[CAND_CAP];
    if (lane == 0) wmx[wv] = m;
    __syncthreads();
    if (tid == 0) {
        float M = wmx[0];
        for (int w = 1; w < 16; ++w) M = fmaxf(M, wmx[w]);
        sM = M; scnt = 0; sovf = 0;
    }
    __syncthreads();
    const float M = sM;

    // 2) candidates: upper bound >= M
    for (int r = tid; r < V_DIM; r += 1024) {
        float2 le = LE[r];
        if (le.x + le.y >= M) {
            int p = atomicAdd(&scnt, 1);
            if (p < CAND_CAP) clist[p] = r; else sovf = 1;
        }
    }
    __syncthreads();
    const int n = scnt < CAND_CAP ? scnt : CAND_CAP;
    const int ovf = sovf;

    // 3) exact fp32 recompute
    float4 hr[2][2];
    load_h_frag(h, hr, lane);
    unsigned long long bestp = 0ull;
    if (!ovf) {
        for (int ci = wv; ci < n; ci += 16) {
            int row = clist[ci];
            float s = row_dot_f32(Wlin + (size_t)row * H_DIM, hr, lane) + blin[row];
            unsigned long long p =
                ((unsigned long long)fmap(s) << 32) | (unsigned)(0xFFFFFFFFu - (unsigned)row);
            if (p > bestp) bestp = p;
        }
    } else {  // safety net: full exact argmax (never expected)
        for (int row = wv; row < V_DIM; row += 16) {
            float s = row_dot_f32(Wlin + (size_t)row * H_DIM, hr, lane) + blin[row];
            unsigned long long p =
                ((unsigned long long)fmap(s) << 32) | (unsigned)(0xFFFFFFFFu - (unsigned)row);
            if (p > bestp) bestp = p;
        }
    }
    __shared__ unsigned long long sbp[16];
    __shared__ int stok;
    if (lane == 0) sbp[wv] = bestp;
    __syncthreads();
    if (tid == 0) {
        unsigned long long B = sbp[0];
        for (int w = 1; w < 16; ++w) if (sbp[w] > B) B = sbp[w];
        int tok = (int)(0xFFFFFFFFu - (unsigned)(B & 0xFFFFFFFFu));
        stok = tok;
        *tok_out = tok;
    }
    __syncthreads();
    int tok = stok;
    const float4* e4 = (const float4*)(emb + (size_t)tok * E_DIM);
    float4* xo = (float4*)x;
    if (tid < E_DIM / 4) xo[tid] = e4[tid];
}

extern "C" void kernel_launch(void* const* d_in, const int* in_sizes, int n_in,
                              void* d_out, int out_size, void* d_ws, size_t ws_size,
                              hipStream_t stream) {
    const float* inp  = (const float*)d_in[0];
    const float* Wih  = (const float*)d_in[1];
    const float* Whh  = (const float*)d_in[2];
    const float* bih  = (const float*)d_in[3];
    const float* bhh  = (const float*)d_in[4];
    const float* emb  = (const float*)d_in[5];
    const float* Wlin = (const float*)d_in[6];
    const float* blin = (const float*)d_in[7];
    int* toks = (int*)d_out;

    char* ws = (char*)d_ws;
    float* x     = (float*)(ws + OFF_X);
    float* h     = (float*)(ws + OFF_H);
    float* c     = (float*)(ws + OFF_C);
    float* gates = (float*)(ws + OFF_GATES);
    float* hn    = (float*)(ws + OFF_HN);
    unsigned long long* partials = (unsigned long long*)(ws + OFF_PART);
    float* pblock = (float*)(ws + OFF_PBLOCK);
    float* nrm   = (float*)(ws + OFF_NRM);
    float2* LE   = (float2*)(ws + OFF_LE);
    unsigned* Wb = (unsigned*)(ws + OFF_WB);

    const int useBf = (ws_size >= WS_NEEDED) ? 1 : 0;

    init_kernel<<<1, 1024, 0, stream>>>(inp, x, h, c);

    for (int step = 0; step < NSTEPS; ++step) {
        gates_kernel<<<NB_GATES, 256, 0, stream>>>(Wih, Whh, bih, bhh, x, h, gates);
        cell_kernel<<<1, 1024, 0, stream>>>(gates, c, h, hn);
        if (step == 0 || !useBf) {
            logits_f32_kernel<<<NB_LOG, 256, 0, stream>>>(
                Wlin, blin, h, Wb, nrm, (step == 0 && useBf) ? 1 : 0, partials);
            finalize_f32_kernel<<<1, 256, 0, stream>>>(partials, emb, x, toks + step);
        } else {
            logits_bf16_kernel<<<NB_LOG, 256, 0, stream>>>(Wb, blin, h, nrm, hn, LE, pblock);
            finalize_bf16_kernel<<<1, 1024, 0, stream>>>(LE, pblock, Wlin, blin, h, emb,
                                                         x, toks + step);
        }
    }
}

// Round 5
// 681.601 us; speedup vs baseline: 5.3431x; 1.2635x over previous
//
#include <hip/hip_runtime.h>
#include <hip/hip_bf16.h>
#include <math.h>

#define E_DIM 512
#define H_DIM 1024
#define V_DIM 50257
#define NSTEPS 19
#define NB_LOG 1024      // logits blocks (4 waves each)
#define NB_GATES 256
#define RPW 13           // rows per wave (4096 waves * 13 = 53248 >= V)
#define RPB 52           // rows per block (4 waves * 13)
#define CAND_CAP 512
#define BL_CAP 64
#define EPS_SCALE 0.00390625f   // 2^-8; true bf16 bound ~2^-9 -> 2x margin

// ---- workspace layout (bytes), NO overlaps ----
#define OFF_X      0          // 512 f    (ends 2048)
#define OFF_H      4096       // 1024 f   (ends 8192)
#define OFF_C      8192       // 1024 f   (ends 12288)
#define OFF_C2     12288      // 1024 f   (ends 16384)
#define OFF_GATES  16384      // 4096 f   (ends 32768)
#define OFF_HN     32768      // 1 f
#define OFF_PART   33024      // 1024 u64 (ends 41216)
#define OFF_PBLOCK 41216      // 1024 float2 (ends 49408)
#define OFF_NRM    57344      // 50257 f  (ends 258372, pad to 262144)
#define OFF_LE     262144     // 50257 float2 (ends 664200, pad to 671744)
#define OFF_WB     671744     // bf16 W_lin 50257*1024*2
#define WS_NEEDED  (671744ull + (unsigned long long)V_DIM * H_DIM * 2ull)

__device__ inline unsigned fmap(float f) {
    unsigned u = __float_as_uint(f);
    return (u & 0x80000000u) ? ~u : (u | 0x80000000u);
}
__device__ inline float bf_lo(unsigned u) { return __uint_as_float(u << 16); }
__device__ inline float bf_hi(unsigned u) { return __uint_as_float(u & 0xFFFF0000u); }
__device__ inline unsigned f2bf(float f) {
    unsigned u = __float_as_uint(f);
    return (u + 0x7FFFu + ((u >> 16) & 1u)) >> 16;
}
__device__ inline float sigm(float v) { return 1.0f / (1.0f + expf(-v)); }

__device__ inline float row_dot_f32(const float* __restrict__ Wrow,
                                    const float4 hr[2][2], int lane) {
    const float4* w4 = (const float4*)Wrow;
    float s = 0.f;
#pragma unroll
    for (int j = 0; j < 2; ++j) {
        int q = lane + 64 * j;
        float4 A = w4[2 * q];
        float4 B = w4[2 * q + 1];
        s = fmaf(A.x, hr[j][0].x, s); s = fmaf(A.y, hr[j][0].y, s);
        s = fmaf(A.z, hr[j][0].z, s); s = fmaf(A.w, hr[j][0].w, s);
        s = fmaf(B.x, hr[j][1].x, s); s = fmaf(B.y, hr[j][1].y, s);
        s = fmaf(B.z, hr[j][1].z, s); s = fmaf(B.w, hr[j][1].w, s);
    }
#pragma unroll
    for (int off = 32; off; off >>= 1) s += __shfl_xor(s, off, 64);
    return s;
}

__device__ inline void load_h_frag(const float* __restrict__ h, float4 hr[2][2], int lane) {
    const float4* h4 = (const float4*)h;
#pragma unroll
    for (int j = 0; j < 2; ++j) {
        int q = lane + 64 * j;
        hr[j][0] = h4[2 * q];
        hr[j][1] = h4[2 * q + 1];
    }
}

// ---------------- init ----------------
__global__ void init_kernel(const float* __restrict__ inp,
                            float* __restrict__ x, float* __restrict__ h,
                            float* __restrict__ c) {
    int i = threadIdx.x;  // 1024
    if (i < E_DIM) x[i] = inp[i];
    h[i] = 0.f; c[i] = 0.f;
}

// ---------------- gates matvec ----------------
__global__ void gates_kernel(const float* __restrict__ Wih,
                             const float* __restrict__ Whh,
                             const float* __restrict__ bih,
                             const float* __restrict__ bhh,
                             const float* __restrict__ x,
                             const float* __restrict__ h,
                             float* __restrict__ gates) {
    const int lane = threadIdx.x & 63, wave = threadIdx.x >> 6;
    const int gw = blockIdx.x * 4 + wave;
    const int NW = NB_GATES * 4;

    const float4* x4 = (const float4*)x;
    const float4* h4 = (const float4*)h;
    float4 xr[2], hr[4];
#pragma unroll
    for (int j = 0; j < 2; ++j) xr[j] = x4[lane + j * 64];
#pragma unroll
    for (int j = 0; j < 4; ++j) hr[j] = h4[lane + j * 64];

    for (int row = gw; row < 4 * H_DIM; row += NW) {
        const float4* wi = (const float4*)(Wih + (size_t)row * E_DIM);
        const float4* wh = (const float4*)(Whh + (size_t)row * H_DIM);
        float s = 0.f;
#pragma unroll
        for (int j = 0; j < 2; ++j) {
            float4 w = wi[lane + j * 64];
            s = fmaf(w.x, xr[j].x, s); s = fmaf(w.y, xr[j].y, s);
            s = fmaf(w.z, xr[j].z, s); s = fmaf(w.w, xr[j].w, s);
        }
#pragma unroll
        for (int j = 0; j < 4; ++j) {
            float4 w = wh[lane + j * 64];
            s = fmaf(w.x, hr[j].x, s); s = fmaf(w.y, hr[j].y, s);
            s = fmaf(w.z, hr[j].z, s); s = fmaf(w.w, hr[j].w, s);
        }
#pragma unroll
        for (int off = 32; off; off >>= 1) s += __shfl_xor(s, off, 64);
        if (lane == 0) gates[row] = s + bih[row] + bhh[row];
    }
}

// ---------------- standalone LSTM cell (step 0 / fallback) ----------------
__global__ void cell_kernel(const float* __restrict__ gates,
                            float* __restrict__ c, float* __restrict__ h,
                            float* __restrict__ hn) {
    int j = threadIdx.x;  // 1024, 1 block
    float iv = sigm(gates[j]);
    float fv = sigm(gates[j + H_DIM]);
    float gv = tanhf(gates[j + 2 * H_DIM]);
    float ov = sigm(gates[j + 3 * H_DIM]);
    float cv = fv * c[j] + iv * gv;
    c[j] = cv;
    float hv = ov * tanhf(cv);
    h[j] = hv;

    float sq = hv * hv;
#pragma unroll
    for (int off = 32; off; off >>= 1) sq += __shfl_xor(sq, off, 64);
    __shared__ float ws[16];
    int lane = j & 63, wv = j >> 6;
    if (lane == 0) ws[wv] = sq;
    __syncthreads();
    if (j == 0) {
        float t = 0.f;
        for (int w = 0; w < 16; ++w) t += ws[w];
        *hn = sqrtf(t);
    }
}

// ---------------- step-0: fp32 logits + bf16 convert + ||w~||_2 ----------------
__global__ void logits_f32_kernel(const float* __restrict__ Wlin,
                                  const float* __restrict__ blin,
                                  const float* __restrict__ h,
                                  unsigned* __restrict__ Wb,
                                  float* __restrict__ nrm, int doConv,
                                  unsigned long long* __restrict__ partials) {
    const int tid = threadIdx.x, lane = tid & 63, wave = tid >> 6;
    const int gw = blockIdx.x * 4 + wave;

    float4 hr[2][2];
    load_h_frag(h, hr, lane);

    float best = -INFINITY;
    int bidx = 0x7fffffff;
    for (int row = gw; row < V_DIM; row += NB_LOG * 4) {
        const float4* w4 = (const float4*)(Wlin + (size_t)row * H_DIM);
        float s = 0.f, s2 = 0.f;
#pragma unroll
        for (int j = 0; j < 2; ++j) {
            int q = lane + 64 * j;
            float4 A = w4[2 * q];
            float4 B = w4[2 * q + 1];
            s = fmaf(A.x, hr[j][0].x, s); s = fmaf(A.y, hr[j][0].y, s);
            s = fmaf(A.z, hr[j][0].z, s); s = fmaf(A.w, hr[j][0].w, s);
            s = fmaf(B.x, hr[j][1].x, s); s = fmaf(B.y, hr[j][1].y, s);
            s = fmaf(B.z, hr[j][1].z, s); s = fmaf(B.w, hr[j][1].w, s);
            if (doConv) {
                uint4 p;
                p.x = f2bf(A.x) | (f2bf(A.y) << 16);
                p.y = f2bf(A.z) | (f2bf(A.w) << 16);
                p.z = f2bf(B.x) | (f2bf(B.y) << 16);
                p.w = f2bf(B.z) | (f2bf(B.w) << 16);
                ((uint4*)(Wb + (size_t)row * 512))[q] = p;
                float w0 = bf_lo(p.x), w1 = bf_hi(p.x), w2 = bf_lo(p.y), w3 = bf_hi(p.y);
                float w4_ = bf_lo(p.z), w5 = bf_hi(p.z), w6 = bf_lo(p.w), w7 = bf_hi(p.w);
                s2 = fmaf(w0, w0, s2); s2 = fmaf(w1, w1, s2);
                s2 = fmaf(w2, w2, s2); s2 = fmaf(w3, w3, s2);
                s2 = fmaf(w4_, w4_, s2); s2 = fmaf(w5, w5, s2);
                s2 = fmaf(w6, w6, s2); s2 = fmaf(w7, w7, s2);
            }
        }
#pragma unroll
        for (int off = 32; off; off >>= 1) {
            s += __shfl_xor(s, off, 64);
            if (doConv) s2 += __shfl_xor(s2, off, 64);
        }
        if (doConv && lane == 0) nrm[row] = sqrtf(s2);
        s += blin[row];
        if (s > best) { best = s; bidx = row; }
    }

    __shared__ float bv[4];
    __shared__ int bi[4];
    if (lane == 0) { bv[wave] = best; bi[wave] = bidx; }
    __syncthreads();
    if (tid == 0) {
        float B = bv[0]; int I = bi[0];
        for (int w = 1; w < 4; ++w)
            if (bv[w] > B || (bv[w] == B && bi[w] < I)) { B = bv[w]; I = bi[w]; }
        partials[blockIdx.x] =
            ((unsigned long long)fmap(B) << 32) | (unsigned)(0xFFFFFFFFu - (unsigned)I);
    }
}

__global__ void finalize_f32_kernel(const unsigned long long* __restrict__ partials,
                                    const float* __restrict__ emb,
                                    float* __restrict__ x, int* __restrict__ tok_out) {
    const int lane = threadIdx.x & 63, wave = threadIdx.x >> 6;
    unsigned long long best = 0ull;
    for (int i = threadIdx.x; i < NB_LOG; i += 256) {
        unsigned long long p = partials[i];
        if (p > best) best = p;
    }
#pragma unroll
    for (int off = 32; off; off >>= 1) {
        unsigned long long o = __shfl_xor(best, off, 64);
        if (o > best) best = o;
    }
    __shared__ unsigned long long sb[4];
    __shared__ int stok;
    if (lane == 0) sb[wave] = best;
    __syncthreads();
    if (threadIdx.x == 0) {
        unsigned long long B = sb[0];
        for (int w = 1; w < 4; ++w) if (sb[w] > B) B = sb[w];
        int tok = (int)(0xFFFFFFFFu - (unsigned)(B & 0xFFFFFFFFu));
        *tok_out = tok;
        stok = tok;
    }
    __syncthreads();
    int tok = stok;
    if (tok < 0) tok = 0;
    if (tok >= V_DIM) tok = V_DIM - 1;
    const float4* e4 = (const float4*)(emb + (size_t)tok * E_DIM);
    float4* x4 = (float4*)x;
    if (threadIdx.x < E_DIM / 4) x4[threadIdx.x] = e4[threadIdx.x];
}

// ------- bf16 logits with fused LSTM cell -------
// Every wave recomputes full h from gates+c_in in registers (gates is L2-hot).
// Block 0 / wave 0 additionally writes h and c_out to global.
__global__ void logits_bf16_kernel(const unsigned* __restrict__ Wb,
                                   const float* __restrict__ blin,
                                   const float* __restrict__ gates,
                                   const float* __restrict__ cin,
                                   float* __restrict__ cout,
                                   float* __restrict__ hout,
                                   const float* __restrict__ nrm,
                                   float2* __restrict__ LE,
                                   float2* __restrict__ pblock) {
    const int tid = threadIdx.x, lane = tid & 63, wave = tid >> 6;
    const int wid = blockIdx.x * 4 + wave;
    const int r0 = wid * RPW;
    int nrows = V_DIM - r0;
    nrows = nrows < 0 ? 0 : (nrows > RPW ? RPW : nrows);

    // prefetch first row of Wb early (independent of h)
    const uint4* base = (const uint4*)(Wb + (size_t)r0 * 512);
    uint4 p0, p1;
    if (nrows > 0) { p0 = base[lane]; p1 = base[lane + 64]; }

    // ---- fused cell: every wave computes all 1024 h elements (16 per lane) ----
    const float4* g4i = (const float4*)gates;
    const float4* g4f = (const float4*)(gates + H_DIM);
    const float4* g4g = (const float4*)(gates + 2 * H_DIM);
    const float4* g4o = (const float4*)(gates + 3 * H_DIM);
    const float4* c4  = (const float4*)cin;

    float4 hr[2][2], cn[2][2];
    float sq = 0.f;
#pragma unroll
    for (int j = 0; j < 2; ++j) {
        int q = lane + 64 * j;
#pragma unroll
        for (int u = 0; u < 2; ++u) {
            int v = 2 * q + u;
            float4 gi = g4i[v], gf = g4f[v], gg = g4g[v], go = g4o[v], cc = c4[v];
            float4 hv, cv;
            cv.x = sigm(gf.x) * cc.x + sigm(gi.x) * tanhf(gg.x);
            cv.y = sigm(gf.y) * cc.y + sigm(gi.y) * tanhf(gg.y);
            cv.z = sigm(gf.z) * cc.z + sigm(gi.z) * tanhf(gg.z);
            cv.w = sigm(gf.w) * cc.w + sigm(gi.w) * tanhf(gg.w);
            hv.x = sigm(go.x) * tanhf(cv.x);
            hv.y = sigm(go.y) * tanhf(cv.y);
            hv.z = sigm(go.z) * tanhf(cv.z);
            hv.w = sigm(go.w) * tanhf(cv.w);
            hr[j][u] = hv; cn[j][u] = cv;
            sq = fmaf(hv.x, hv.x, sq); sq = fmaf(hv.y, hv.y, sq);
            sq = fmaf(hv.z, hv.z, sq); sq = fmaf(hv.w, hv.w, sq);
        }
    }
#pragma unroll
    for (int off = 32; off; off >>= 1) sq += __shfl_xor(sq, off, 64);
    const float K = EPS_SCALE * sqrtf(sq);   // eps * ||h||_2

    if (blockIdx.x == 0 && wave == 0) {      // single writer for h, c_out
        float4* h4o = (float4*)hout;
        float4* c4o = (float4*)cout;
#pragma unroll
        for (int j = 0; j < 2; ++j) {
            int q = lane + 64 * j;
            h4o[2 * q] = hr[j][0]; h4o[2 * q + 1] = hr[j][1];
            c4o[2 * q] = cn[j][0]; c4o[2 * q + 1] = cn[j][1];
        }
    }

    // ---- bf16 rows, double-buffered loads ----
    float maxl = -INFINITY, maxu = -INFINITY;
    for (int k = 0; k < nrows; ++k) {
        uint4 c0 = p0, c1 = p1;
        if (k + 1 < nrows) {
            const uint4* nb = base + (size_t)(k + 1) * 128;
            p0 = nb[lane]; p1 = nb[lane + 64];
        }
        float s = 0.f;
        {
            float w0 = bf_lo(c0.x), w1 = bf_hi(c0.x), w2 = bf_lo(c0.y), w3 = bf_hi(c0.y);
            float w4_ = bf_lo(c0.z), w5 = bf_hi(c0.z), w6 = bf_lo(c0.w), w7 = bf_hi(c0.w);
            s = fmaf(w0, hr[0][0].x, s); s = fmaf(w1, hr[0][0].y, s);
            s = fmaf(w2, hr[0][0].z, s); s = fmaf(w3, hr[0][0].w, s);
            s = fmaf(w4_, hr[0][1].x, s); s = fmaf(w5, hr[0][1].y, s);
            s = fmaf(w6, hr[0][1].z, s); s = fmaf(w7, hr[0][1].w, s);
        }
        {
            float w0 = bf_lo(c1.x), w1 = bf_hi(c1.x), w2 = bf_lo(c1.y), w3 = bf_hi(c1.y);
            float w4_ = bf_lo(c1.z), w5 = bf_hi(c1.z), w6 = bf_lo(c1.w), w7 = bf_hi(c1.w);
            s = fmaf(w0, hr[1][0].x, s); s = fmaf(w1, hr[1][0].y, s);
            s = fmaf(w2, hr[1][0].z, s); s = fmaf(w3, hr[1][0].w, s);
            s = fmaf(w4_, hr[1][1].x, s); s = fmaf(w5, hr[1][1].y, s);
            s = fmaf(w6, hr[1][1].z, s); s = fmaf(w7, hr[1][1].w, s);
        }
#pragma unroll
        for (int off = 32; off; off >>= 1) s += __shfl_xor(s, off, 64);
        int r = r0 + k;
        float L = s + blin[r];
        float e = K * nrm[r];
        if (lane == 0) LE[r] = make_float2(L, e);
        maxl = fmaxf(maxl, L - e);
        maxu = fmaxf(maxu, L + e);
    }

    __shared__ float wl[4], wu[4];
    if (lane == 0) { wl[wave] = maxl; wu[wave] = maxu; }
    __syncthreads();
    if (tid == 0) {
        float lo = fmaxf(fmaxf(wl[0], wl[1]), fmaxf(wl[2], wl[3]));
        float up = fmaxf(fmaxf(wu[0], wu[1]), fmaxf(wu[2], wu[3]));
        pblock[blockIdx.x] = make_float2(lo, up);
    }
}

// ------- bf16 finalize: block-filtered candidate scan + exact rescue -------
__global__ void finalize_bf16_kernel(const float2* __restrict__ LE,
                                     const float2* __restrict__ pblock,
                                     const float* __restrict__ Wlin,
                                     const float* __restrict__ blin,
                                     const float* __restrict__ h,
                                     const float* __restrict__ emb,
                                     float* __restrict__ x, int* __restrict__ tok_out) {
    const int tid = threadIdx.x;              // 1024 threads
    const int lane = tid & 63, wv = tid >> 6; // 16 waves

    __shared__ float wmx[16];
    __shared__ float sM;
    __shared__ int snb, sncand, sovf;
    __shared__ int blist[BL_CAP];
    __shared__ int clist[CAND_CAP];

    // 1) M = max lower bound over blocks
    float2 pb = pblock[tid];
    float m = pb.x;
#pragma unroll
    for (int off = 32; off; off >>= 1) m = fmaxf(m, __shfl_xor(m, off, 64));
    if (lane == 0) wmx[wv] = m;
    __syncthreads();
    if (tid == 0) {
        float M = wmx[0];
        for (int w = 1; w < 16; ++w) M = fmaxf(M, wmx[w]);
        sM = M; snb = 0; sncand = 0; sovf = 0;
    }
    __syncthreads();
    const float M = sM;

    // 2) candidate blocks: max upper >= M
    if (pb.y >= M) {
        int p = atomicAdd(&snb, 1);
        if (p < BL_CAP) blist[p] = tid; else sovf = 1;
    }
    __syncthreads();

    // 3) candidate rows
    if (!sovf) {
        int nb = snb < BL_CAP ? snb : BL_CAP;
        for (int bi = 0; bi < nb; ++bi) {
            int b = blist[bi];
            int r = b * RPB + tid;
            if (tid < RPB && r < V_DIM) {
                float2 le = LE[r];
                if (le.x + le.y >= M) {
                    int p = atomicAdd(&sncand, 1);
                    if (p < CAND_CAP) clist[p] = r; else sovf = 1;
                }
            }
            __syncthreads();
        }
    } else {  // too many blocks: scan all rows (correct slow path)
        for (int r = tid; r < V_DIM; r += 1024) {
            float2 le = LE[r];
            if (le.x + le.y >= M) {
                int p = atomicAdd(&sncand, 1);
                if (p < CAND_CAP) clist[p] = r; else sovf = 1;
            }
        }
        __syncthreads();
    }
    __syncthreads();
    // defensive: zero candidates (bound invariant violated) -> full exact scan
    if (tid == 0 && sncand == 0) sovf = 1;
    __syncthreads();
    const int n = sncand < CAND_CAP ? sncand : CAND_CAP;
    const int ovf = sovf;

    // 4) exact fp32 rescue
    float4 hr[2][2];
    load_h_frag(h, hr, lane);
    unsigned long long bestp = 0ull;
    if (!ovf) {
        for (int ci = wv; ci < n; ci += 16) {
            int row = clist[ci];
            float s = row_dot_f32(Wlin + (size_t)row * H_DIM, hr, lane) + blin[row];
            unsigned long long p =
                ((unsigned long long)fmap(s) << 32) | (unsigned)(0xFFFFFFFFu - (unsigned)row);
            if (p > bestp) bestp = p;
        }
    } else {  // overflow or empty: full exact argmax
        for (int row = wv; row < V_DIM; row += 16) {
            float s = row_dot_f32(Wlin + (size_t)row * H_DIM, hr, lane) + blin[row];
            unsigned long long p =
                ((unsigned long long)fmap(s) << 32) | (unsigned)(0xFFFFFFFFu - (unsigned)row);
            if (p > bestp) bestp = p;
        }
    }
    __shared__ unsigned long long sbp[16];
    __shared__ int stok;
    if (lane == 0) sbp[wv] = bestp;
    __syncthreads();
    if (tid == 0) {
        unsigned long long B = sbp[0];
        for (int w = 1; w < 16; ++w) if (sbp[w] > B) B = sbp[w];
        int tok = (int)(0xFFFFFFFFu - (unsigned)(B & 0xFFFFFFFFu));
        stok = tok;
        *tok_out = tok;
    }
    __syncthreads();
    int tok = stok;
    if (tok < 0) tok = 0;               // clamp gather only; real tok already stored
    if (tok >= V_DIM) tok = V_DIM - 1;
    const float4* e4 = (const float4*)(emb + (size_t)tok * E_DIM);
    float4* xo = (float4*)x;
    if (tid < E_DIM / 4) xo[tid] = e4[tid];
}

extern "C" void kernel_launch(void* const* d_in, const int* in_sizes, int n_in,
                              void* d_out, int out_size, void* d_ws, size_t ws_size,
                              hipStream_t stream) {
    const float* inp  = (const float*)d_in[0];
    const float* Wih  = (const float*)d_in[1];
    const float* Whh  = (const float*)d_in[2];
    const float* bih  = (const float*)d_in[3];
    const float* bhh  = (const float*)d_in[4];
    const float* emb  = (const float*)d_in[5];
    const float* Wlin = (const float*)d_in[6];
    const float* blin = (const float*)d_in[7];
    int* toks = (int*)d_out;

    char* ws = (char*)d_ws;
    float* x     = (float*)(ws + OFF_X);
    float* h     = (float*)(ws + OFF_H);
    float* c0b   = (float*)(ws + OFF_C);
    float* c1b   = (float*)(ws + OFF_C2);
    float* gates = (float*)(ws + OFF_GATES);
    float* hn    = (float*)(ws + OFF_HN);
    unsigned long long* partials = (unsigned long long*)(ws + OFF_PART);
    float2* pblock = (float2*)(ws + OFF_PBLOCK);
    float* nrm   = (float*)(ws + OFF_NRM);
    float2* LE   = (float2*)(ws + OFF_LE);
    unsigned* Wb = (unsigned*)(ws + OFF_WB);

    const int useBf = (ws_size >= WS_NEEDED) ? 1 : 0;

    init_kernel<<<1, 1024, 0, stream>>>(inp, x, h, c0b);

    for (int step = 0; step < NSTEPS; ++step) {
        gates_kernel<<<NB_GATES, 256, 0, stream>>>(Wih, Whh, bih, bhh, x, h, gates);
        if (step == 0 || !useBf) {
            cell_kernel<<<1, 1024, 0, stream>>>(gates, c0b, h, hn);
            logits_f32_kernel<<<NB_LOG, 256, 0, stream>>>(
                Wlin, blin, h, Wb, nrm, (step == 0 && useBf) ? 1 : 0, partials);
            finalize_f32_kernel<<<1, 256, 0, stream>>>(partials, emb, x, toks + step);
        } else {
            float* cin  = (step & 1) ? c0b : c1b;   // step1 reads c0b
            float* cout = (step & 1) ? c1b : c0b;
            logits_bf16_kernel<<<NB_LOG, 256, 0, stream>>>(
                Wb, blin, gates, cin, cout, h, nrm, LE, pblock);
            finalize_bf16_kernel<<<1, 1024, 0, stream>>>(LE, pblock, Wlin, blin, h, emb,
                                                         x, toks + step);
        }
    }
}

// Round 6
// 583.653 us; speedup vs baseline: 6.2397x; 1.1678x over previous
//
#include <hip/hip_runtime.h>
#include <hip/hip_bf16.h>
#include <math.h>

#define E_DIM 512
#define H_DIM 1024
#define V_DIM 50257
#define NSTEPS 19
#define NB_F32 1024      // fp32 logits blocks (4 waves each)
#define NB_LOG 512       // bf16 logits blocks (8 waves each) -> 4096 waves
#define RPW 13           // rows per wave (4096*13 = 53248 >= V)
#define RPB 104          // rows per bf16 block (8*13)
#define NB_GATES 256
#define BL_CAP 128
#define CAND_CAP 512
#define EPS_SCALE 0.00390625f   // 2^-8; true bf16 bound ~2^-9 -> 2x margin

// ---- workspace layout (bytes), NO overlaps ----
#define OFF_X      0          // 512 f
#define OFF_H      4096       // 1024 f
#define OFF_C      8192       // 1024 f (ping)
#define OFF_C2     12288      // 1024 f (pong)
#define OFF_GATES  16384      // 4096 f
#define OFF_HN     32768      // 1 f
#define OFF_PART   33024      // 1024 u64 (ends 41216)
#define OFF_PBLOCK 41216      // 512 float2 (ends 45312)
#define OFF_NRM    57344      // 50257 f (ends 258372)
#define OFF_LE     262144     // 50257 float2 (ends 664200)
#define OFF_WB     671744     // bf16 W_lin 50257*1024*2
#define WS_NEEDED  (671744ull + (unsigned long long)V_DIM * H_DIM * 2ull)

__device__ inline unsigned fmap(float f) {
    unsigned u = __float_as_uint(f);
    return (u & 0x80000000u) ? ~u : (u | 0x80000000u);
}
__device__ inline unsigned long long packmax(float s, int row) {
    return ((unsigned long long)fmap(s) << 32) | (unsigned)(0xFFFFFFFFu - (unsigned)row);
}
__device__ inline float bf_lo(unsigned u) { return __uint_as_float(u << 16); }
__device__ inline float bf_hi(unsigned u) { return __uint_as_float(u & 0xFFFF0000u); }
__device__ inline unsigned f2bf(float f) {
    unsigned u = __float_as_uint(f);
    return (u + 0x7FFFu + ((u >> 16) & 1u)) >> 16;
}
__device__ inline float sigm(float v) { return 1.0f / (1.0f + expf(-v)); }

// h fragment layout "hr4": hr[j] = h4[lane + 64j], j<4 (covers all 1024)
__device__ inline void load_h4(const float* __restrict__ h, float4 hr[4], int lane) {
    const float4* h4 = (const float4*)h;
#pragma unroll
    for (int j = 0; j < 4; ++j) hr[j] = h4[lane + 64 * j];
}
// exact fp32 wave-collective row dot using hr4 layout (broadcast to all lanes)
__device__ inline float row_dot4(const float* __restrict__ Wrow,
                                 const float4 hr[4], int lane) {
    const float4* w4 = (const float4*)Wrow;
    float s = 0.f;
#pragma unroll
    for (int j = 0; j < 4; ++j) {
        float4 w = w4[lane + 64 * j];
        s = fmaf(w.x, hr[j].x, s); s = fmaf(w.y, hr[j].y, s);
        s = fmaf(w.z, hr[j].z, s); s = fmaf(w.w, hr[j].w, s);
    }
#pragma unroll
    for (int off = 32; off; off >>= 1) s += __shfl_xor(s, off, 64);
    return s;
}

// ---------------- init ----------------
__global__ void init_kernel(const float* __restrict__ inp,
                            float* __restrict__ x, float* __restrict__ h,
                            float* __restrict__ c) {
    int i = threadIdx.x;  // 1024
    if (i < E_DIM) x[i] = inp[i];
    h[i] = 0.f; c[i] = 0.f;
}

// ---------------- gates matvec, optionally fused with previous-step finalize ----------------
__global__ void gatesfin_kernel(const float* __restrict__ Wih,
                                const float* __restrict__ Whh,
                                const float* __restrict__ bih,
                                const float* __restrict__ bhh,
                                const float* __restrict__ xg,
                                const float* __restrict__ h,
                                float* __restrict__ gates,
                                const float2* __restrict__ LE,
                                const float2* __restrict__ pblock,
                                const float* __restrict__ Wlin,
                                const float* __restrict__ blin,
                                const float* __restrict__ emb,
                                int* __restrict__ tok_out, int doFin) {
    const int tid = threadIdx.x, lane = tid & 63, wave = tid >> 6;  // 256 thr, 4 waves

    float4 hr[4];
    load_h4(h, hr, lane);

    __shared__ float s_wmx[4];
    __shared__ float s_M;
    __shared__ int s_nb, s_nc, s_ovf;
    __shared__ int s_blist[BL_CAP];
    __shared__ int s_clist[CAND_CAP];
    __shared__ unsigned long long s_bp[4];
    __shared__ int s_tok;

    float4 xr[2];
    if (doFin) {
        // ---- finalize of previous step, block-redundant (deterministic) ----
        float2 pb0 = pblock[tid];
        float2 pb1 = pblock[tid + 256];
        float m = fmaxf(pb0.x, pb1.x);
#pragma unroll
        for (int off = 32; off; off >>= 1) m = fmaxf(m, __shfl_xor(m, off, 64));
        if (lane == 0) s_wmx[wave] = m;
        __syncthreads();
        if (tid == 0) {
            s_M = fmaxf(fmaxf(s_wmx[0], s_wmx[1]), fmaxf(s_wmx[2], s_wmx[3]));
            s_nb = 0; s_nc = 0; s_ovf = 0;
        }
        __syncthreads();
        const float M = s_M;
        if (pb0.y >= M) { int p = atomicAdd(&s_nb, 1); if (p < BL_CAP) s_blist[p] = tid; else s_ovf = 1; }
        if (pb1.y >= M) { int p = atomicAdd(&s_nb, 1); if (p < BL_CAP) s_blist[p] = tid + 256; else s_ovf = 1; }
        __syncthreads();
        if (!s_ovf) {
            int nb = s_nb < BL_CAP ? s_nb : BL_CAP;
            for (int bi = 0; bi < nb; ++bi) {
                int r = s_blist[bi] * RPB + tid;
                if (tid < RPB && r < V_DIM) {
                    float2 le = LE[r];
                    if (le.x + le.y >= M) {
                        int p = atomicAdd(&s_nc, 1);
                        if (p < CAND_CAP) s_clist[p] = r; else s_ovf = 1;
                    }
                }
                __syncthreads();
            }
        }
        __syncthreads();
        if (tid == 0 && s_nc == 0) s_ovf = 1;   // defensive (cannot happen if bounds sound)
        __syncthreads();
        const int ovf = s_ovf;
        const int n = s_nc < CAND_CAP ? s_nc : CAND_CAP;

        unsigned long long bestp = 0ull;
        if (!ovf) {
            for (int ci = wave; ci < n; ci += 4) {
                int row = s_clist[ci];
                float s = row_dot4(Wlin + (size_t)row * H_DIM, hr, lane) + blin[row];
                unsigned long long p = packmax(s, row);
                if (p > bestp) bestp = p;
            }
        } else {  // safety net: full exact argmax (never expected)
            for (int row = wave; row < V_DIM; row += 4) {
                float s = row_dot4(Wlin + (size_t)row * H_DIM, hr, lane) + blin[row];
                unsigned long long p = packmax(s, row);
                if (p > bestp) bestp = p;
            }
        }
        if (lane == 0) s_bp[wave] = bestp;
        __syncthreads();
        if (tid == 0) {
            unsigned long long B = s_bp[0];
            for (int w = 1; w < 4; ++w) if (s_bp[w] > B) B = s_bp[w];
            int tok = (int)(0xFFFFFFFFu - (unsigned)(B & 0xFFFFFFFFu));
            s_tok = tok;
            *tok_out = tok;
        }
        __syncthreads();
        int tokc = s_tok;
        if (tokc < 0) tokc = 0;
        if (tokc >= V_DIM) tokc = V_DIM - 1;
        const float4* e4 = (const float4*)(emb + (size_t)tokc * E_DIM);
        xr[0] = e4[lane]; xr[1] = e4[lane + 64];
    } else {
        const float4* x4 = (const float4*)xg;
        xr[0] = x4[lane]; xr[1] = x4[lane + 64];
    }

    // ---- gates matvec: 4096 rows over 1024 waves ----
    for (int row = blockIdx.x * 4 + wave; row < 4 * H_DIM; row += NB_GATES * 4) {
        const float4* wi = (const float4*)(Wih + (size_t)row * E_DIM);
        const float4* wh = (const float4*)(Whh + (size_t)row * H_DIM);
        float s = 0.f;
#pragma unroll
        for (int j = 0; j < 2; ++j) {
            float4 w = wi[lane + j * 64];
            s = fmaf(w.x, xr[j].x, s); s = fmaf(w.y, xr[j].y, s);
            s = fmaf(w.z, xr[j].z, s); s = fmaf(w.w, xr[j].w, s);
        }
#pragma unroll
        for (int j = 0; j < 4; ++j) {
            float4 w = wh[lane + j * 64];
            s = fmaf(w.x, hr[j].x, s); s = fmaf(w.y, hr[j].y, s);
            s = fmaf(w.z, hr[j].z, s); s = fmaf(w.w, hr[j].w, s);
        }
#pragma unroll
        for (int off = 32; off; off >>= 1) s += __shfl_xor(s, off, 64);
        if (lane == 0) gates[row] = s + bih[row] + bhh[row];
    }
}

// ---------------- standalone LSTM cell (step 0 / fallback) ----------------
__global__ void cell_kernel(const float* __restrict__ gates,
                            float* __restrict__ c, float* __restrict__ h,
                            float* __restrict__ hn) {
    int j = threadIdx.x;  // 1024, 1 block
    float iv = sigm(gates[j]);
    float fv = sigm(gates[j + H_DIM]);
    float gv = tanhf(gates[j + 2 * H_DIM]);
    float ov = sigm(gates[j + 3 * H_DIM]);
    float cv = fv * c[j] + iv * gv;
    c[j] = cv;
    float hv = ov * tanhf(cv);
    h[j] = hv;

    float sq = hv * hv;
#pragma unroll
    for (int off = 32; off; off >>= 1) sq += __shfl_xor(sq, off, 64);
    __shared__ float ws[16];
    int lane = j & 63, wv = j >> 6;
    if (lane == 0) ws[wv] = sq;
    __syncthreads();
    if (j == 0) {
        float t = 0.f;
        for (int w = 0; w < 16; ++w) t += ws[w];
        *hn = sqrtf(t);
    }
}

// ---------------- step-0: fp32 logits + bf16 convert + ||w~||_2 ----------------
__global__ void logits_f32_kernel(const float* __restrict__ Wlin,
                                  const float* __restrict__ blin,
                                  const float* __restrict__ h,
                                  unsigned* __restrict__ Wb,
                                  float* __restrict__ nrm, int doConv,
                                  unsigned long long* __restrict__ partials) {
    const int tid = threadIdx.x, lane = tid & 63, wave = tid >> 6;
    const int gw = blockIdx.x * 4 + wave;

    float4 hr[4];
    load_h4(h, hr, lane);

    float best = -INFINITY;
    int bidx = 0x7fffffff;
    for (int row = gw; row < V_DIM; row += NB_F32 * 4) {
        const float4* w4 = (const float4*)(Wlin + (size_t)row * H_DIM);
        float s = 0.f, s2 = 0.f;
#pragma unroll
        for (int j = 0; j < 4; ++j) {
            float4 A = w4[lane + 64 * j];
            s = fmaf(A.x, hr[j].x, s); s = fmaf(A.y, hr[j].y, s);
            s = fmaf(A.z, hr[j].z, s); s = fmaf(A.w, hr[j].w, s);
            if (doConv) {
                uint2 p;
                p.x = f2bf(A.x) | (f2bf(A.y) << 16);
                p.y = f2bf(A.z) | (f2bf(A.w) << 16);
                ((uint2*)(Wb + (size_t)row * 512))[lane + 64 * j] = p;
                float w0 = bf_lo(p.x), w1 = bf_hi(p.x), w2 = bf_lo(p.y), w3 = bf_hi(p.y);
                s2 = fmaf(w0, w0, s2); s2 = fmaf(w1, w1, s2);
                s2 = fmaf(w2, w2, s2); s2 = fmaf(w3, w3, s2);
            }
        }
#pragma unroll
        for (int off = 32; off; off >>= 1) {
            s += __shfl_xor(s, off, 64);
            if (doConv) s2 += __shfl_xor(s2, off, 64);
        }
        if (doConv && lane == 0) nrm[row] = sqrtf(s2);
        s += blin[row];
        if (s > best) { best = s; bidx = row; }
    }

    __shared__ float bv[4];
    __shared__ int bi[4];
    if (lane == 0) { bv[wave] = best; bi[wave] = bidx; }
    __syncthreads();
    if (tid == 0) {
        float B = bv[0]; int I = bi[0];
        for (int w = 1; w < 4; ++w)
            if (bv[w] > B || (bv[w] == B && bi[w] < I)) { B = bv[w]; I = bi[w]; }
        partials[blockIdx.x] = packmax(B, I);
    }
}

__global__ void finalize_f32_kernel(const unsigned long long* __restrict__ partials,
                                    const float* __restrict__ emb,
                                    float* __restrict__ x, int* __restrict__ tok_out) {
    const int lane = threadIdx.x & 63, wave = threadIdx.x >> 6;
    unsigned long long best = 0ull;
    for (int i = threadIdx.x; i < NB_F32; i += 256) {
        unsigned long long p = partials[i];
        if (p > best) best = p;
    }
#pragma unroll
    for (int off = 32; off; off >>= 1) {
        unsigned long long o = __shfl_xor(best, off, 64);
        if (o > best) best = o;
    }
    __shared__ unsigned long long sb[4];
    __shared__ int stok;
    if (lane == 0) sb[wave] = best;
    __syncthreads();
    if (threadIdx.x == 0) {
        unsigned long long B = sb[0];
        for (int w = 1; w < 4; ++w) if (sb[w] > B) B = sb[w];
        int tok = (int)(0xFFFFFFFFu - (unsigned)(B & 0xFFFFFFFFu));
        *tok_out = tok;
        stok = tok;
    }
    __syncthreads();
    int tok = stok;
    if (tok < 0) tok = 0;
    if (tok >= V_DIM) tok = V_DIM - 1;
    const float4* e4 = (const float4*)(emb + (size_t)tok * E_DIM);
    float4* x4 = (float4*)x;
    if (threadIdx.x < E_DIM / 4) x4[threadIdx.x] = e4[threadIdx.x];
}

// ------- bf16 logits with cooperative (LDS) fused LSTM cell -------
// 512 threads = 8 waves; waves 0-3 compute h,c into LDS; all waves consume.
__global__ void logits_bf16_kernel(const unsigned* __restrict__ Wb,
                                   const float* __restrict__ blin,
                                   const float* __restrict__ gates,
                                   const float* __restrict__ cin,
                                   float* __restrict__ cout,
                                   float* __restrict__ hout,
                                   const float* __restrict__ nrm,
                                   float2* __restrict__ LE,
                                   float2* __restrict__ pblock) {
    const int tid = threadIdx.x, lane = tid & 63, wave = tid >> 6;  // 8 waves
    const int wid = blockIdx.x * 8 + wave;
    const int r0 = wid * RPW;
    int nrows = V_DIM - r0;
    nrows = nrows < 0 ? 0 : (nrows > RPW ? RPW : nrows);

    // prefetch first row of Wb early (independent of h)
    const uint4* base = (const uint4*)(Wb + (size_t)r0 * 512);
    uint4 p0, p1;
    if (nrows > 0) { p0 = base[lane]; p1 = base[lane + 64]; }

    __shared__ float h_lds[H_DIM];
    __shared__ float cpart[4];

    if (wave < 4) {
        const int idx4 = wave * 64 + lane;  // float4 index 0..255
        const float4* g4i = (const float4*)gates;
        const float4* g4f = (const float4*)(gates + H_DIM);
        const float4* g4g = (const float4*)(gates + 2 * H_DIM);
        const float4* g4o = (const float4*)(gates + 3 * H_DIM);
        const float4* c4  = (const float4*)cin;
        float4 gi = g4i[idx4], gf = g4f[idx4], gg = g4g[idx4], go = g4o[idx4], cc = c4[idx4];
        float4 hv, cv;
        cv.x = sigm(gf.x) * cc.x + sigm(gi.x) * tanhf(gg.x);
        cv.y = sigm(gf.y) * cc.y + sigm(gi.y) * tanhf(gg.y);
        cv.z = sigm(gf.z) * cc.z + sigm(gi.z) * tanhf(gg.z);
        cv.w = sigm(gf.w) * cc.w + sigm(gi.w) * tanhf(gg.w);
        hv.x = sigm(go.x) * tanhf(cv.x);
        hv.y = sigm(go.y) * tanhf(cv.y);
        hv.z = sigm(go.z) * tanhf(cv.z);
        hv.w = sigm(go.w) * tanhf(cv.w);
        ((float4*)h_lds)[idx4] = hv;
        if (blockIdx.x == 0) {
            ((float4*)hout)[idx4] = hv;
            ((float4*)cout)[idx4] = cv;
        }
        float sq = fmaf(hv.x, hv.x, fmaf(hv.y, hv.y, fmaf(hv.z, hv.z, hv.w * hv.w)));
#pragma unroll
        for (int off = 32; off; off >>= 1) sq += __shfl_xor(sq, off, 64);
        if (lane == 0) cpart[wave] = sq;
    }
    __syncthreads();
    const float K = EPS_SCALE * sqrtf(cpart[0] + cpart[1] + cpart[2] + cpart[3]);

    // h fragment for bf16 dot: lane needs h[8*lane .. +7] and h[512+8*lane .. +7]
    float4 hr[2][2];
#pragma unroll
    for (int j = 0; j < 2; ++j) {
        int q = lane + 64 * j;
        hr[j][0] = ((const float4*)h_lds)[2 * q];
        hr[j][1] = ((const float4*)h_lds)[2 * q + 1];
    }

    // ---- bf16 rows, double-buffered loads ----
    float maxl = -INFINITY, maxu = -INFINITY;
    for (int k = 0; k < nrows; ++k) {
        uint4 c0 = p0, c1 = p1;
        if (k + 1 < nrows) {
            const uint4* nb = base + (size_t)(k + 1) * 128;
            p0 = nb[lane]; p1 = nb[lane + 64];
        }
        float s = 0.f;
        {
            float w0 = bf_lo(c0.x), w1 = bf_hi(c0.x), w2 = bf_lo(c0.y), w3 = bf_hi(c0.y);
            float w4_ = bf_lo(c0.z), w5 = bf_hi(c0.z), w6 = bf_lo(c0.w), w7 = bf_hi(c0.w);
            s = fmaf(w0, hr[0][0].x, s); s = fmaf(w1, hr[0][0].y, s);
            s = fmaf(w2, hr[0][0].z, s); s = fmaf(w3, hr[0][0].w, s);
            s = fmaf(w4_, hr[0][1].x, s); s = fmaf(w5, hr[0][1].y, s);
            s = fmaf(w6, hr[0][1].z, s); s = fmaf(w7, hr[0][1].w, s);
        }
        {
            float w0 = bf_lo(c1.x), w1 = bf_hi(c1.x), w2 = bf_lo(c1.y), w3 = bf_hi(c1.y);
            float w4_ = bf_lo(c1.z), w5 = bf_hi(c1.z), w6 = bf_lo(c1.w), w7 = bf_hi(c1.w);
            s = fmaf(w0, hr[1][0].x, s); s = fmaf(w1, hr[1][0].y, s);
            s = fmaf(w2, hr[1][0].z, s); s = fmaf(w3, hr[1][0].w, s);
            s = fmaf(w4_, hr[1][1].x, s); s = fmaf(w5, hr[1][1].y, s);
            s = fmaf(w6, hr[1][1].z, s); s = fmaf(w7, hr[1][1].w, s);
        }
#pragma unroll
        for (int off = 32; off; off >>= 1) s += __shfl_xor(s, off, 64);
        int r = r0 + k;
        float L = s + blin[r];
        float e = K * nrm[r];
        if (lane == 0) LE[r] = make_float2(L, e);
        maxl = fmaxf(maxl, L - e);
        maxu = fmaxf(maxu, L + e);
    }

    __shared__ float wl[8], wu[8];
    if (lane == 0) { wl[wave] = maxl; wu[wave] = maxu; }
    __syncthreads();
    if (tid == 0) {
        float lo = wl[0], up = wu[0];
        for (int w = 1; w < 8; ++w) { lo = fmaxf(lo, wl[w]); up = fmaxf(up, wu[w]); }
        pblock[blockIdx.x] = make_float2(lo, up);
    }
}

// ------- standalone bf16 finalize (last step only) -------
__global__ void finalize_bf16_kernel(const float2* __restrict__ LE,
                                     const float2* __restrict__ pblock,
                                     const float* __restrict__ Wlin,
                                     const float* __restrict__ blin,
                                     const float* __restrict__ h,
                                     const float* __restrict__ emb,
                                     float* __restrict__ x, int* __restrict__ tok_out) {
    const int tid = threadIdx.x;              // 1024 threads
    const int lane = tid & 63, wv = tid >> 6; // 16 waves

    __shared__ float wmx[16];
    __shared__ float sM;
    __shared__ int snb, sncand, sovf;
    __shared__ int blist[BL_CAP];
    __shared__ int clist[CAND_CAP];

    float2 pb = make_float2(-INFINITY, -INFINITY);
    if (tid < NB_LOG) pb = pblock[tid];
    float m = pb.x;
#pragma unroll
    for (int off = 32; off; off >>= 1) m = fmaxf(m, __shfl_xor(m, off, 64));
    if (lane == 0) wmx[wv] = m;
    __syncthreads();
    if (tid == 0) {
        float M = wmx[0];
        for (int w = 1; w < 16; ++w) M = fmaxf(M, wmx[w]);
        sM = M; snb = 0; sncand = 0; sovf = 0;
    }
    __syncthreads();
    const float M = sM;

    if (tid < NB_LOG && pb.y >= M) {
        int p = atomicAdd(&snb, 1);
        if (p < BL_CAP) blist[p] = tid; else sovf = 1;
    }
    __syncthreads();
    if (!sovf) {
        int nb = snb < BL_CAP ? snb : BL_CAP;
        for (int bi = 0; bi < nb; ++bi) {
            int r = blist[bi] * RPB + tid;
            if (tid < RPB && r < V_DIM) {
                float2 le = LE[r];
                if (le.x + le.y >= M) {
                    int p = atomicAdd(&sncand, 1);
                    if (p < CAND_CAP) clist[p] = r; else sovf = 1;
                }
            }
            __syncthreads();
        }
    }
    __syncthreads();
    if (tid == 0 && sncand == 0) sovf = 1;
    __syncthreads();
    const int ovf = sovf;
    const int n = sncand < CAND_CAP ? sncand : CAND_CAP;

    float4 hr[4];
    load_h4(h, hr, lane);
    unsigned long long bestp = 0ull;
    if (!ovf) {
        for (int ci = wv; ci < n; ci += 16) {
            int row = clist[ci];
            float s = row_dot4(Wlin + (size_t)row * H_DIM, hr, lane) + blin[row];
            unsigned long long p = packmax(s, row);
            if (p > bestp) bestp = p;
        }
    } else {
        for (int row = wv; row < V_DIM; row += 16) {
            float s = row_dot4(Wlin + (size_t)row * H_DIM, hr, lane) + blin[row];
            unsigned long long p = packmax(s, row);
            if (p > bestp) bestp = p;
        }
    }
    __shared__ unsigned long long sbp[16];
    __shared__ int stok;
    if (lane == 0) sbp[wv] = bestp;
    __syncthreads();
    if (tid == 0) {
        unsigned long long B = sbp[0];
        for (int w = 1; w < 16; ++w) if (sbp[w] > B) B = sbp[w];
        int tok = (int)(0xFFFFFFFFu - (unsigned)(B & 0xFFFFFFFFu));
        stok = tok;
        *tok_out = tok;
    }
    __syncthreads();
    int tok = stok;
    if (tok < 0) tok = 0;
    if (tok >= V_DIM) tok = V_DIM - 1;
    const float4* e4 = (const float4*)(emb + (size_t)tok * E_DIM);
    float4* xo = (float4*)x;
    if (tid < E_DIM / 4) xo[tid] = e4[tid];
}

extern "C" void kernel_launch(void* const* d_in, const int* in_sizes, int n_in,
                              void* d_out, int out_size, void* d_ws, size_t ws_size,
                              hipStream_t stream) {
    const float* inp  = (const float*)d_in[0];
    const float* Wih  = (const float*)d_in[1];
    const float* Whh  = (const float*)d_in[2];
    const float* bih  = (const float*)d_in[3];
    const float* bhh  = (const float*)d_in[4];
    const float* emb  = (const float*)d_in[5];
    const float* Wlin = (const float*)d_in[6];
    const float* blin = (const float*)d_in[7];
    int* toks = (int*)d_out;

    char* ws = (char*)d_ws;
    float* x     = (float*)(ws + OFF_X);
    float* h     = (float*)(ws + OFF_H);
    float* c0b   = (float*)(ws + OFF_C);
    float* c1b   = (float*)(ws + OFF_C2);
    float* gates = (float*)(ws + OFF_GATES);
    float* hn    = (float*)(ws + OFF_HN);
    unsigned long long* partials = (unsigned long long*)(ws + OFF_PART);
    float2* pblock = (float2*)(ws + OFF_PBLOCK);
    float* nrm   = (float*)(ws + OFF_NRM);
    float2* LE   = (float2*)(ws + OFF_LE);
    unsigned* Wb = (unsigned*)(ws + OFF_WB);

    const int useBf = (ws_size >= WS_NEEDED) ? 1 : 0;

    init_kernel<<<1, 1024, 0, stream>>>(inp, x, h, c0b);

    if (!useBf) {
        for (int step = 0; step < NSTEPS; ++step) {
            gatesfin_kernel<<<NB_GATES, 256, 0, stream>>>(
                Wih, Whh, bih, bhh, x, h, gates, LE, pblock, Wlin, blin, emb,
                (int*)nullptr, 0);
            cell_kernel<<<1, 1024, 0, stream>>>(gates, c0b, h, hn);
            logits_f32_kernel<<<NB_F32, 256, 0, stream>>>(
                Wlin, blin, h, Wb, nrm, 0, partials);
            finalize_f32_kernel<<<1, 256, 0, stream>>>(partials, emb, x, toks + step);
        }
        return;
    }

    // ---- step 0: fp32 scan + bf16 conversion ----
    gatesfin_kernel<<<NB_GATES, 256, 0, stream>>>(
        Wih, Whh, bih, bhh, x, h, gates, LE, pblock, Wlin, blin, emb,
        (int*)nullptr, 0);
    cell_kernel<<<1, 1024, 0, stream>>>(gates, c0b, h, hn);   // h_0, c_0 (in c0b)
    logits_f32_kernel<<<NB_F32, 256, 0, stream>>>(
        Wlin, blin, h, Wb, nrm, 1, partials);
    finalize_f32_kernel<<<1, 256, 0, stream>>>(partials, emb, x, toks + 0);

    // ---- steps 1..18: 2 kernels per step ----
    for (int t = 1; t < NSTEPS; ++t) {
        gatesfin_kernel<<<NB_GATES, 256, 0, stream>>>(
            Wih, Whh, bih, bhh, x, h, gates, LE, pblock, Wlin, blin, emb,
            (t >= 2) ? (toks + t - 1) : (int*)nullptr, (t >= 2) ? 1 : 0);
        float* cin  = (t & 1) ? c0b : c1b;
        float* cout = (t & 1) ? c1b : c0b;
        logits_bf16_kernel<<<NB_LOG, 512, 0, stream>>>(
            Wb, blin, gates, cin, cout, h, nrm, LE, pblock);
    }
    // tail: finalize step 18
    finalize_bf16_kernel<<<1, 1024, 0, stream>>>(LE, pblock, Wlin, blin, h, emb,
                                                 x, toks + NSTEPS - 1);
}